// Round 14
// baseline (99.168 us; speedup 1.0000x reference)
//
#include <hip/hip_runtime.h>
#include <math.h>

#define B_ 8
#define N_ 2048
#define H_ 256

typedef double d4 __attribute__((ext_vector_type(4)));

// One-shot: W1T[k][o] = W1[o][k] (f32, 256 KB in d_ws) -> unit-stride reads.
__global__ __launch_bounds__(256)
void transpose_w1(const float* __restrict__ W1, float* __restrict__ W1T) {
    W1T[(size_t)blockIdx.x * H_ + threadIdx.x] =
        W1[(size_t)threadIdx.x * H_ + blockIdx.x];
}

// Layout probe for v_mfma_f64_16x16x4_f64 (standard CDNA mapping check):
//  A: row=l&15, k=l>>4;  B: col=l&15, k=l>>4;  D: col=l&15, row=4*(l>>4)+v.
//  pw[0]=100 (A-row-0 sum of lane ids via b=1), pw[1]=100 (B-col-0 dual),
//  pw[2]=0 (D[0][1] of A[i][k]=i), pw[3]=24 (D[6][0]=4*6 of same).
__global__ __launch_bounds__(64)
void probe_kernel(double* __restrict__ pw) {
    const int l = threadIdx.x;
    d4 z = {0.0, 0.0, 0.0, 0.0};
    d4 r1 = __builtin_amdgcn_mfma_f64_16x16x4f64((double)(l + 1), 1.0, z, 0, 0, 0);
    d4 r2 = __builtin_amdgcn_mfma_f64_16x16x4f64(1.0, (double)(l + 1), z, 0, 0, 0);
    d4 r3 = __builtin_amdgcn_mfma_f64_16x16x4f64((double)(l & 15), 1.0, z, 0, 0, 0);
    if (l == 0)  { pw[0] = r1[0]; pw[1] = r2[0]; }
    if (l == 1)  { pw[2] = r3[0]; }
    if (l == 16) { pw[3] = r3[2]; }
}

__device__ __forceinline__ bool layout_ok(const double* pw) {
    return pw[0] == 100.0 && pw[1] == 100.0 && pw[2] == 0.0 && pw[3] == 24.0;
}

// MFMA-path s kernel: runs ONLY if the probe confirmed the layout.
// 16 rows/block, 4 waves; wave owns a 64-o strip (4 o-tiles of 16).
// Per 4-k chunk: 1 A dword + 4 B dwords per lane + 4 mfma_f64 (2048 FLOP ea).
__global__ __launch_bounds__(256)
void s_mfma_kernel(const float* __restrict__ hp, const float* __restrict__ W1T,
                   const float* __restrict__ b1, const float* __restrict__ w2,
                   double* __restrict__ s_out, const double* __restrict__ pw) {
    if (!layout_ok(pw)) return;    // VALU kernel will do the work
    __shared__ double spart[4][16];
    const int t = threadIdx.x;
    const int lane = t & 63;
    const int wave = __builtin_amdgcn_readfirstlane(t >> 6);
    const int a15 = lane & 15, g = lane >> 4;
    const int m0 = blockIdx.x * 16;
    const int oc = wave * 64;
    const float* ap = hp + (size_t)(m0 + a15) * H_ + g;   // A: h[m0+a15][kc+g]
    const float* bp = W1T + (size_t)g * H_ + oc + a15;    // B: W1T[kc+g][oc+ot*16+a15]

    d4 acc[4];
    #pragma unroll
    for (int ot = 0; ot < 4; ++ot) acc[ot] = (d4){0.0, 0.0, 0.0, 0.0};

    float ac, bc[4], an, bn[4];
    ac = ap[0];
    #pragma unroll
    for (int ot = 0; ot < 4; ++ot) bc[ot] = bp[ot * 16];

    for (int kc = 0; kc < H_; kc += 4) {
        const int kn = (kc + 4 < H_) ? (kc + 4) : 0;      // guarded prefetch
        an = ap[kn];
        #pragma unroll
        for (int ot = 0; ot < 4; ++ot)
            bn[ot] = bp[(size_t)kn * H_ + ot * 16];
        const double av = (double)ac;
        #pragma unroll
        for (int ot = 0; ot < 4; ++ot)
            acc[ot] = __builtin_amdgcn_mfma_f64_16x16x4f64(
                av, (double)bc[ot], acc[ot], 0, 0, 0);
        ac = an;
        #pragma unroll
        for (int ot = 0; ot < 4; ++ot) bc[ot] = bn[ot];
    }

    // Lane holds D rows m = m0+4g+v, col o = oc+ot*16+a15.
    double psum[4] = {0.0, 0.0, 0.0, 0.0};
    #pragma unroll
    for (int ot = 0; ot < 4; ++ot) {
        const int o = oc + ot * 16 + a15;
        const double bb = (double)b1[o];
        const double ww = (double)w2[o];
        #pragma unroll
        for (int v = 0; v < 4; ++v) {
            const double u = acc[ot][v] + bb;
            psum[v] += ww * (u / (1.0 + exp(-u)));   // silu in f64
        }
    }
    // Reduce over the 16 a-lanes; rows stay per (g,v).
    #pragma unroll
    for (int v = 0; v < 4; ++v) {
        double x = psum[v];
        x += __shfl_xor(x, 1, 64);
        x += __shfl_xor(x, 2, 64);
        x += __shfl_xor(x, 4, 64);
        x += __shfl_xor(x, 8, 64);
        psum[v] = x;
    }
    if (a15 == 0) {
        #pragma unroll
        for (int v = 0; v < 4; ++v) spart[wave][g * 4 + v] = psum[v];
    }
    __syncthreads();
    if (t < 16)
        s_out[m0 + t] = spart[0][t] + spart[1][t] + spart[2][t] + spart[3][t];
}

// VALU fallback s kernel (round-11 verified body): runs only if probe FAILED.
__global__ __launch_bounds__(256)
__attribute__((amdgpu_waves_per_eu(2, 4)))
void s_valu_kernel(const float* __restrict__ hp, const float* __restrict__ W1T,
                   const float* __restrict__ b1, const float* __restrict__ w2,
                   double* __restrict__ s_out, const double* __restrict__ pw) {
    if (layout_ok(pw)) return;     // MFMA kernel did the work
    const int t = threadIdx.x;
    const int lane = t & 63;
    const int wave = __builtin_amdgcn_readfirstlane(t >> 6);
    const int m0 = blockIdx.x * 16 + wave * 4;
    const int o0 = lane * 4;
    const float* hr = hp + (size_t)m0 * H_;
    const float* wp = W1T + o0;

    double acc[4][4];
    #pragma unroll
    for (int j = 0; j < 4; ++j)
        #pragma unroll
        for (int r = 0; r < 4; ++r) acc[j][r] = 0.0;

    float4 wA[8], wB[8];
    float hA[32], hB[32];

    #define LOADW(dst, kcv)                                                   \
        do {                                                                  \
            _Pragma("unroll")                                                 \
            for (int kk = 0; kk < 8; ++kk)                                    \
                dst[kk] = *reinterpret_cast<const float4*>(                   \
                    wp + (size_t)((kcv) + kk) * H_);                          \
        } while (0)

    #define LOADH(dst, kcv)                                                   \
        do {                                                                  \
            _Pragma("unroll")                                                 \
            for (int r = 0; r < 4; ++r)                                       \
                _Pragma("unroll")                                             \
                for (int kk = 0; kk < 8; ++kk)                                \
                    dst[r * 8 + kk] = hr[r * H_ + (kcv) + kk];                \
        } while (0)

    #define COMPUTE(wv, hbuf)                                                 \
        do {                                                                  \
            _Pragma("unroll")                                                 \
            for (int kk = 0; kk < 8; ++kk) {                                  \
                const double h0 = (double)hbuf[0 * 8 + kk];                   \
                const double h1 = (double)hbuf[1 * 8 + kk];                   \
                const double h2 = (double)hbuf[2 * 8 + kk];                   \
                const double h3 = (double)hbuf[3 * 8 + kk];                   \
                const double a0 = (double)wv[kk].x;                           \
                const double a1 = (double)wv[kk].y;                           \
                const double a2 = (double)wv[kk].z;                           \
                const double a3 = (double)wv[kk].w;                           \
                acc[0][0] = fma(a0, h0, acc[0][0]);                           \
                acc[0][1] = fma(a0, h1, acc[0][1]);                           \
                acc[0][2] = fma(a0, h2, acc[0][2]);                           \
                acc[0][3] = fma(a0, h3, acc[0][3]);                           \
                acc[1][0] = fma(a1, h0, acc[1][0]);                           \
                acc[1][1] = fma(a1, h1, acc[1][1]);                           \
                acc[1][2] = fma(a1, h2, acc[1][2]);                           \
                acc[1][3] = fma(a1, h3, acc[1][3]);                           \
                acc[2][0] = fma(a2, h0, acc[2][0]);                           \
                acc[2][1] = fma(a2, h1, acc[2][1]);                           \
                acc[2][2] = fma(a2, h2, acc[2][2]);                           \
                acc[2][3] = fma(a2, h3, acc[2][3]);                           \
                acc[3][0] = fma(a3, h0, acc[3][0]);                           \
                acc[3][1] = fma(a3, h1, acc[3][1]);                           \
                acc[3][2] = fma(a3, h2, acc[3][2]);                           \
                acc[3][3] = fma(a3, h3, acc[3][3]);                           \
            }                                                                 \
        } while (0)

    LOADW(wA, 0);
    LOADH(hA, 0);
    for (int kc = 0; kc < H_; kc += 16) {
        LOADW(wB, kc + 8);
        LOADH(hB, kc + 8);
        COMPUTE(wA, hA);
        if (kc + 16 < H_) {
            LOADW(wA, kc + 16);
            LOADH(hA, kc + 16);
        }
        COMPUTE(wB, hB);
    }
    #undef LOADW
    #undef LOADH
    #undef COMPUTE

    const float4 b1v = *reinterpret_cast<const float4*>(b1 + o0);
    const float4 w2v = *reinterpret_cast<const float4*>(w2 + o0);
    double psum[4] = {0.0, 0.0, 0.0, 0.0};
    #define EPI(j, bc, wc)                                                    \
        do {                                                                  \
            const double bb = (double)bc, ww = (double)wc;                    \
            _Pragma("unroll")                                                 \
            for (int r = 0; r < 4; ++r) {                                     \
                const double u = acc[j][r] + bb;                              \
                psum[r] += ww * (u / (1.0 + exp(-u)));                        \
            }                                                                 \
        } while (0)
    EPI(0, b1v.x, w2v.x);
    EPI(1, b1v.y, w2v.y);
    EPI(2, b1v.z, w2v.z);
    EPI(3, b1v.w, w2v.w);
    #undef EPI

    #pragma unroll
    for (int r = 0; r < 4; ++r) {
        double v = psum[r];
        v += __shfl_xor(v, 1, 64);
        v += __shfl_xor(v, 2, 64);
        v += __shfl_xor(v, 4, 64);
        v += __shfl_xor(v, 8, 64);
        v += __shfl_xor(v, 16, 64);
        v += __shfl_xor(v, 32, 64);
        if (lane == 0) s_out[m0 + r] = v;
    }
}

// Kernel B: out[b,i,j] = (int32)trunc( (s[b,i] - s[b,j]) + b2 )
__global__ __launch_bounds__(256)
void pair_kernel(const double* __restrict__ s, const float* __restrict__ b2p,
                 int* __restrict__ out) {
    const double b2 = (double)b2p[0];
    const unsigned total4 = (unsigned)(B_) * (unsigned)(N_) * (unsigned)(N_) / 4u;
    const unsigned stride = gridDim.x * blockDim.x;
    for (unsigned idx = blockIdx.x * blockDim.x + threadIdx.x; idx < total4;
         idx += stride) {
        const unsigned base = idx * 4u;                 // element index, %4==0
        const unsigned bi  = base >> 22;                // / (N*N), N*N = 2^22
        const unsigned rem = base & ((1u << 22) - 1u);
        const unsigned i   = rem >> 11;                 // / N
        const unsigned j   = rem & (N_ - 1u);
        const double si = s[bi * N_ + i];
        const double* sp = s + bi * N_ + j;             // 32B aligned (j%4==0)
        const double sj0 = sp[0], sj1 = sp[1], sj2 = sp[2], sj3 = sp[3];
        int4 o;
        o.x = (int)trunc((si - sj0) + b2);
        o.y = (int)trunc((si - sj1) + b2);
        o.z = (int)trunc((si - sj2) + b2);
        o.w = (int)trunc((si - sj3) + b2);
        *reinterpret_cast<int4*>(out + base) = o;
    }
}

extern "C" void kernel_launch(void* const* d_in, const int* in_sizes, int n_in,
                              void* d_out, int out_size, void* d_ws, size_t ws_size,
                              hipStream_t stream) {
    const float* hp = (const float*)d_in[0];
    // d_in[1] = node_mask (unused), d_in[2] = n_nodes (unused)
    const float* W1 = (const float*)d_in[3];
    const float* b1 = (const float*)d_in[4];
    const float* w2 = (const float*)d_in[5];
    const float* b2 = (const float*)d_in[6];

    float*  W1T = (float*)d_ws;                                       // 256 KB
    double* s   = (double*)((char*)d_ws + H_ * H_ * sizeof(float));   // 128 KB
    double* pw  = (double*)((char*)d_ws + 384 * 1024);                // 32 B
    int* out = (int*)d_out;

    probe_kernel<<<1, 64, 0, stream>>>(pw);
    transpose_w1<<<H_, H_, 0, stream>>>(W1, W1T);
    s_mfma_kernel<<<(B_ * N_) / 16, 256, 0, stream>>>(hp, W1T, b1, w2, s, pw);
    s_valu_kernel<<<(B_ * N_) / 16, 256, 0, stream>>>(hp, W1T, b1, w2, s, pw);
    pair_kernel<<<2048, 256, 0, stream>>>(s, b2, out);
}

// Round 15
// 91.815 us; speedup vs baseline: 1.0801x; 1.0801x over previous
//
#include <hip/hip_runtime.h>
#include <math.h>

#define B_ 8
#define N_ 2048
#define H_ 256

typedef double d4 __attribute__((ext_vector_type(4)));

// One-shot: W1T[k][o] = W1[o][k] (f32, 256 KB in d_ws) -> unit-stride reads.
__global__ __launch_bounds__(256)
void transpose_w1(const float* __restrict__ W1, float* __restrict__ W1T) {
    W1T[(size_t)blockIdx.x * H_ + threadIdx.x] =
        W1[(size_t)threadIdx.x * H_ + blockIdx.x];
}

// Probe for v_mfma_f64_16x16x4_f64 lane mappings. Sentinels (A,B standard =>):
//  r1 = mfma(a=l+1, b=1):  D[0][0] = 100  (lane0 reg0 is (0,0) in ALL candidates)
//  r2 = mfma(a=1, b=l+1):  D[i][j] = 4j+100; lane0 reg0 -> 100
//  r3 = mfma(a=l&15, b=1): D[i][j] = 4i
//  pw[2] = r3 lane1  reg0: rowcand{4g+v,g+4v}=0 -> 0 ; rowcand{a15}=1 -> 4
//  pw[3] = r3 lane16 reg2: row=4g+v -> 24 ; row=g+4v -> 36 ; row=a15 -> 0
//  pw[4] = r2 lane16 reg2: col=4g+v -> 124 ; col=g+4v -> 136 ; col=a15 -> 100
//  pw[5] = 7777 magic (pw memory liveness)
__global__ __launch_bounds__(64)
void probe_kernel(double* __restrict__ pw) {
    const int l = threadIdx.x;
    d4 z = {0.0, 0.0, 0.0, 0.0};
    d4 r1 = __builtin_amdgcn_mfma_f64_16x16x4f64((double)(l + 1), 1.0, z, 0, 0, 0);
    d4 r2 = __builtin_amdgcn_mfma_f64_16x16x4f64(1.0, (double)(l + 1), z, 0, 0, 0);
    d4 r3 = __builtin_amdgcn_mfma_f64_16x16x4f64((double)(l & 15), 1.0, z, 0, 0, 0);
    if (l == 0)  { pw[0] = r1[0]; pw[1] = r2[0]; pw[5] = 7777.0; }
    if (l == 1)  { pw[2] = r3[0]; }
    if (l == 16) { pw[3] = r3[2]; pw[4] = r2[2]; }
}

// Which D-mapping variant holds (0 = none / A-B nonstandard / pw broken).
__device__ __forceinline__ int layout_var(const double* pw) {
    if (pw[0] != 100.0 || pw[1] != 100.0) return 0;
    if (pw[2] == 0.0 && pw[3] == 24.0)  return 1;   // row=4g+v, col=a15
    if (pw[2] == 0.0 && pw[3] == 36.0)  return 3;   // row=g+4v, col=a15
    if (pw[2] == 4.0 && pw[4] == 124.0) return 2;   // row=a15,  col=4g+v
    if (pw[2] == 4.0 && pw[4] == 136.0) return 4;   // row=a15,  col=g+4v
    return 0;
}

// Diagnostics: spin ~300us ONLY in a failure mode so they crack the top-5.
__global__ void diag_pw_mem_bad(const double* __restrict__ pw, double* sink) {
    if (pw[5] == 7777.0) return;                    // memory fine -> exit
    double x = pw[0] + 1.0;
    for (int i = 0; i < 200000; ++i) x = fma(x, 1.0000001, 1e-30);
    if (x == 12345.6789) sink[6] = x;               // keep loop live
}
__global__ void diag_ab_nonstd(const double* __restrict__ pw, double* sink) {
    if (!(pw[5] == 7777.0 && (pw[0] != 100.0 || pw[1] != 100.0))) return;
    double x = pw[1] + 1.0;
    for (int i = 0; i < 200000; ++i) x = fma(x, 1.0000001, 1e-30);
    if (x == 12345.6789) sink[7] = x;
}

// MFMA s-kernel, D-mapping variant VAR. 16 rows/block, 4 waves; wave owns a
// 64-o strip (4 o-tiles of 16). A: lane gives h[m0+a15][kc+g]; B: lane gives
// W1T[kc+g][oc+ot*16+a15] (standard A/B, verified by pw[0],pw[1]).
template <int VAR>
__global__ __launch_bounds__(256)
void s_mfma_kernel(const float* __restrict__ hp, const float* __restrict__ W1T,
                   const float* __restrict__ b1, const float* __restrict__ w2,
                   double* __restrict__ s_out, const double* __restrict__ pw) {
    if (layout_var(pw) != VAR) return;              // uniform exit
    __shared__ double spart[4][16];
    const int t = threadIdx.x;
    const int lane = t & 63;
    const int wave = __builtin_amdgcn_readfirstlane(t >> 6);
    const int a15 = lane & 15, g = lane >> 4;
    const int m0 = blockIdx.x * 16;
    const int oc = wave * 64;
    const float* ap = hp + (size_t)(m0 + a15) * H_ + g;
    const float* bp = W1T + (size_t)g * H_ + oc + a15;

    d4 acc[4];
    #pragma unroll
    for (int ot = 0; ot < 4; ++ot) acc[ot] = (d4){0.0, 0.0, 0.0, 0.0};

    float ac, bc[4], an, bn[4];
    ac = ap[0];
    #pragma unroll
    for (int ot = 0; ot < 4; ++ot) bc[ot] = bp[ot * 16];

    for (int kc = 0; kc < H_; kc += 4) {
        const int kn = (kc + 4 < H_) ? (kc + 4) : 0;      // guarded prefetch
        an = ap[kn];
        #pragma unroll
        for (int ot = 0; ot < 4; ++ot)
            bn[ot] = bp[(size_t)kn * H_ + ot * 16];
        const double av = (double)ac;
        #pragma unroll
        for (int ot = 0; ot < 4; ++ot)
            acc[ot] = __builtin_amdgcn_mfma_f64_16x16x4f64(
                av, (double)bc[ot], acc[ot], 0, 0, 0);
        ac = an;
        #pragma unroll
        for (int ot = 0; ot < 4; ++ot) bc[ot] = bn[ot];
    }

    if constexpr (VAR == 1 || VAR == 3) {
        // col = a15 (fixed per lane); row = 4g+v (VAR 1) or g+4v (VAR 3).
        double psum[4] = {0.0, 0.0, 0.0, 0.0};
        #pragma unroll
        for (int ot = 0; ot < 4; ++ot) {
            const int o = oc + ot * 16 + a15;
            const double bb = (double)b1[o];
            const double ww = (double)w2[o];
            #pragma unroll
            for (int v = 0; v < 4; ++v) {
                const double u = acc[ot][v] + bb;
                psum[v] += ww * (u / (1.0 + exp(-u)));
            }
        }
        #pragma unroll
        for (int v = 0; v < 4; ++v) {
            double x = psum[v];
            x += __shfl_xor(x, 1, 64);
            x += __shfl_xor(x, 2, 64);
            x += __shfl_xor(x, 4, 64);
            x += __shfl_xor(x, 8, 64);
            psum[v] = x;
        }
        if (a15 == 0) {
            #pragma unroll
            for (int v = 0; v < 4; ++v) {
                const int row = (VAR == 1) ? (g * 4 + v) : (g + 4 * v);
                spart[wave][row] = psum[v];
            }
        }
    } else {
        // row = a15 (fixed per lane); col = 4g+v (VAR 2) or g+4v (VAR 4).
        double ps = 0.0;
        #pragma unroll
        for (int ot = 0; ot < 4; ++ot) {
            #pragma unroll
            for (int v = 0; v < 4; ++v) {
                const int cv = (VAR == 2) ? (4 * g + v) : (g + 4 * v);
                const int o = oc + ot * 16 + cv;
                const double u = acc[ot][v] + (double)b1[o];
                ps += (double)w2[o] * (u / (1.0 + exp(-u)));
            }
        }
        ps += __shfl_xor(ps, 16, 64);
        ps += __shfl_xor(ps, 32, 64);
        if (g == 0) spart[wave][a15] = ps;
    }
    __syncthreads();
    if (t < 16)
        s_out[m0 + t] = spart[0][t] + spart[1][t] + spart[2][t] + spart[3][t];
}

// VALU fallback (round-11 verified body): runs only if NO variant matched.
__global__ __launch_bounds__(256)
__attribute__((amdgpu_waves_per_eu(2, 4)))
void s_valu_kernel(const float* __restrict__ hp, const float* __restrict__ W1T,
                   const float* __restrict__ b1, const float* __restrict__ w2,
                   double* __restrict__ s_out, const double* __restrict__ pw) {
    if (layout_var(pw) != 0) return;
    const int t = threadIdx.x;
    const int lane = t & 63;
    const int wave = __builtin_amdgcn_readfirstlane(t >> 6);
    const int m0 = blockIdx.x * 16 + wave * 4;
    const int o0 = lane * 4;
    const float* hr = hp + (size_t)m0 * H_;
    const float* wp = W1T + o0;

    double acc[4][4];
    #pragma unroll
    for (int j = 0; j < 4; ++j)
        #pragma unroll
        for (int r = 0; r < 4; ++r) acc[j][r] = 0.0;

    float4 wA[8], wB[8];
    float hA[32], hB[32];

    #define LOADW(dst, kcv)                                                   \
        do {                                                                  \
            _Pragma("unroll")                                                 \
            for (int kk = 0; kk < 8; ++kk)                                    \
                dst[kk] = *reinterpret_cast<const float4*>(                   \
                    wp + (size_t)((kcv) + kk) * H_);                          \
        } while (0)

    #define LOADH(dst, kcv)                                                   \
        do {                                                                  \
            _Pragma("unroll")                                                 \
            for (int r = 0; r < 4; ++r)                                       \
                _Pragma("unroll")                                             \
                for (int kk = 0; kk < 8; ++kk)                                \
                    dst[r * 8 + kk] = hr[r * H_ + (kcv) + kk];                \
        } while (0)

    #define COMPUTE(wv, hbuf)                                                 \
        do {                                                                  \
            _Pragma("unroll")                                                 \
            for (int kk = 0; kk < 8; ++kk) {                                  \
                const double h0 = (double)hbuf[0 * 8 + kk];                   \
                const double h1 = (double)hbuf[1 * 8 + kk];                   \
                const double h2 = (double)hbuf[2 * 8 + kk];                   \
                const double h3 = (double)hbuf[3 * 8 + kk];                   \
                const double a0 = (double)wv[kk].x;                           \
                const double a1 = (double)wv[kk].y;                           \
                const double a2 = (double)wv[kk].z;                           \
                const double a3 = (double)wv[kk].w;                           \
                acc[0][0] = fma(a0, h0, acc[0][0]);                           \
                acc[0][1] = fma(a0, h1, acc[0][1]);                           \
                acc[0][2] = fma(a0, h2, acc[0][2]);                           \
                acc[0][3] = fma(a0, h3, acc[0][3]);                           \
                acc[1][0] = fma(a1, h0, acc[1][0]);                           \
                acc[1][1] = fma(a1, h1, acc[1][1]);                           \
                acc[1][2] = fma(a1, h2, acc[1][2]);                           \
                acc[1][3] = fma(a1, h3, acc[1][3]);                           \
                acc[2][0] = fma(a2, h0, acc[2][0]);                           \
                acc[2][1] = fma(a2, h1, acc[2][1]);                           \
                acc[2][2] = fma(a2, h2, acc[2][2]);                           \
                acc[2][3] = fma(a2, h3, acc[2][3]);                           \
                acc[3][0] = fma(a3, h0, acc[3][0]);                           \
                acc[3][1] = fma(a3, h1, acc[3][1]);                           \
                acc[3][2] = fma(a3, h2, acc[3][2]);                           \
                acc[3][3] = fma(a3, h3, acc[3][3]);                           \
            }                                                                 \
        } while (0)

    LOADW(wA, 0);
    LOADH(hA, 0);
    for (int kc = 0; kc < H_; kc += 16) {
        LOADW(wB, kc + 8);
        LOADH(hB, kc + 8);
        COMPUTE(wA, hA);
        if (kc + 16 < H_) {
            LOADW(wA, kc + 16);
            LOADH(hA, kc + 16);
        }
        COMPUTE(wB, hB);
    }
    #undef LOADW
    #undef LOADH
    #undef COMPUTE

    const float4 b1v = *reinterpret_cast<const float4*>(b1 + o0);
    const float4 w2v = *reinterpret_cast<const float4*>(w2 + o0);
    double psum[4] = {0.0, 0.0, 0.0, 0.0};
    #define EPI(j, bc, wc)                                                    \
        do {                                                                  \
            const double bb = (double)bc, ww = (double)wc;                    \
            _Pragma("unroll")                                                 \
            for (int r = 0; r < 4; ++r) {                                     \
                const double u = acc[j][r] + bb;                              \
                psum[r] += ww * (u / (1.0 + exp(-u)));                        \
            }                                                                 \
        } while (0)
    EPI(0, b1v.x, w2v.x);
    EPI(1, b1v.y, w2v.y);
    EPI(2, b1v.z, w2v.z);
    EPI(3, b1v.w, w2v.w);
    #undef EPI

    #pragma unroll
    for (int r = 0; r < 4; ++r) {
        double v = psum[r];
        v += __shfl_xor(v, 1, 64);
        v += __shfl_xor(v, 2, 64);
        v += __shfl_xor(v, 4, 64);
        v += __shfl_xor(v, 8, 64);
        v += __shfl_xor(v, 16, 64);
        v += __shfl_xor(v, 32, 64);
        if (lane == 0) s_out[m0 + r] = v;
    }
}

// Kernel B: out[b,i,j] = (int32)trunc( (s[b,i] - s[b,j]) + b2 )
__global__ __launch_bounds__(256)
void pair_kernel(const double* __restrict__ s, const float* __restrict__ b2p,
                 int* __restrict__ out) {
    const double b2 = (double)b2p[0];
    const unsigned total4 = (unsigned)(B_) * (unsigned)(N_) * (unsigned)(N_) / 4u;
    const unsigned stride = gridDim.x * blockDim.x;
    for (unsigned idx = blockIdx.x * blockDim.x + threadIdx.x; idx < total4;
         idx += stride) {
        const unsigned base = idx * 4u;                 // element index, %4==0
        const unsigned bi  = base >> 22;                // / (N*N), N*N = 2^22
        const unsigned rem = base & ((1u << 22) - 1u);
        const unsigned i   = rem >> 11;                 // / N
        const unsigned j   = rem & (N_ - 1u);
        const double si = s[bi * N_ + i];
        const double* sp = s + bi * N_ + j;             // 32B aligned (j%4==0)
        const double sj0 = sp[0], sj1 = sp[1], sj2 = sp[2], sj3 = sp[3];
        int4 o;
        o.x = (int)trunc((si - sj0) + b2);
        o.y = (int)trunc((si - sj1) + b2);
        o.z = (int)trunc((si - sj2) + b2);
        o.w = (int)trunc((si - sj3) + b2);
        *reinterpret_cast<int4*>(out + base) = o;
    }
}

extern "C" void kernel_launch(void* const* d_in, const int* in_sizes, int n_in,
                              void* d_out, int out_size, void* d_ws, size_t ws_size,
                              hipStream_t stream) {
    const float* hp = (const float*)d_in[0];
    // d_in[1] = node_mask (unused), d_in[2] = n_nodes (unused)
    const float* W1 = (const float*)d_in[3];
    const float* b1 = (const float*)d_in[4];
    const float* w2 = (const float*)d_in[5];
    const float* b2 = (const float*)d_in[6];

    float*  W1T = (float*)d_ws;                                       // 256 KB
    double* s   = (double*)((char*)d_ws + H_ * H_ * sizeof(float));   // 128 KB
    double* pw  = (double*)((char*)d_ws + 384 * 1024);                // 64 B
    int* out = (int*)d_out;

    probe_kernel<<<1, 64, 0, stream>>>(pw);
    transpose_w1<<<H_, H_, 0, stream>>>(W1, W1T);
    diag_pw_mem_bad<<<1, 64, 0, stream>>>(pw, pw);
    diag_ab_nonstd<<<1, 64, 0, stream>>>(pw, pw);
    s_mfma_kernel<1><<<(B_ * N_) / 16, 256, 0, stream>>>(hp, W1T, b1, w2, s, pw);
    s_mfma_kernel<2><<<(B_ * N_) / 16, 256, 0, stream>>>(hp, W1T, b1, w2, s, pw);
    s_mfma_kernel<3><<<(B_ * N_) / 16, 256, 0, stream>>>(hp, W1T, b1, w2, s, pw);
    s_mfma_kernel<4><<<(B_ * N_) / 16, 256, 0, stream>>>(hp, W1T, b1, w2, s, pw);
    s_valu_kernel<<<(B_ * N_) / 16, 256, 0, stream>>>(hp, W1T, b1, w2, s, pw);
    pair_kernel<<<2048, 256, 0, stream>>>(s, b2, out);
}

// Round 16
// 81.522 us; speedup vs baseline: 1.2165x; 1.1263x over previous
//
#include <hip/hip_runtime.h>
#include <math.h>

#define B_ 8
#define N_ 2048
#define H_ 256

typedef double d4 __attribute__((ext_vector_type(4)));

// One-shot: W1T[k][o] = W1[o][k] (f32, 256 KB in d_ws) -> unit-stride reads.
__global__ __launch_bounds__(256)
void transpose_w1(const float* __restrict__ W1, float* __restrict__ W1T) {
    W1T[(size_t)blockIdx.x * H_ + threadIdx.x] =
        W1[(size_t)threadIdx.x * H_ + blockIdx.x];
}

// Probe for v_mfma_f64_16x16x4_f64 lane mappings (see round-15 notes).
__global__ __launch_bounds__(64)
void probe_kernel(double* __restrict__ pw) {
    const int l = threadIdx.x;
    d4 z = {0.0, 0.0, 0.0, 0.0};
    d4 r1 = __builtin_amdgcn_mfma_f64_16x16x4f64((double)(l + 1), 1.0, z, 0, 0, 0);
    d4 r2 = __builtin_amdgcn_mfma_f64_16x16x4f64(1.0, (double)(l + 1), z, 0, 0, 0);
    d4 r3 = __builtin_amdgcn_mfma_f64_16x16x4f64((double)(l & 15), 1.0, z, 0, 0, 0);
    if (l == 0)  { pw[0] = r1[0]; pw[1] = r2[0]; pw[5] = 7777.0; }
    if (l == 1)  { pw[2] = r3[0]; }
    if (l == 16) { pw[3] = r3[2]; pw[4] = r2[2]; }
}

// D-mapping variant (0 = none/nonstandard-A/B; round 15 proved one of 1-4
// matches on this chip).
__device__ __forceinline__ int layout_var(const double* pw) {
    if (pw[0] != 100.0 || pw[1] != 100.0) return 0;
    if (pw[2] == 0.0 && pw[3] == 24.0)  return 1;   // row=4g+v, col=a15
    if (pw[2] == 0.0 && pw[3] == 36.0)  return 3;   // row=g+4v, col=a15
    if (pw[2] == 4.0 && pw[4] == 124.0) return 2;   // row=a15,  col=4g+v
    if (pw[2] == 4.0 && pw[4] == 136.0) return 4;   // row=a15,  col=g+4v
    return 0;
}

// Consolidated MFMA s-kernel: GEMM body is mapping-independent; only the
// epilogue branches on the (wave-uniform) runtime variant.
// 16 rows/block, 4 waves; wave owns a 64-o strip (4 o-tiles of 16).
// Inner loop: 8 k per iter = 8 mfma (512 cy issue) + 2 A + 8 B loads,
// prefetched one full iteration ahead (covers L2 ~220 cy).
__global__ __launch_bounds__(256)
__attribute__((amdgpu_waves_per_eu(2, 4)))
void s_mfma_uni(const float* __restrict__ hp, const float* __restrict__ W1T,
                const float* __restrict__ b1, const float* __restrict__ w2,
                double* __restrict__ s_out, const double* __restrict__ pw) {
    const int var = layout_var(pw);
    if (var == 0) return;                       // VALU fallback does the work
    __shared__ double spart[4][16];
    const int t = threadIdx.x;
    const int lane = t & 63;
    const int wave = __builtin_amdgcn_readfirstlane(t >> 6);
    const int a15 = lane & 15, g = lane >> 4;
    const int m0 = blockIdx.x * 16;
    const int oc = wave * 64;
    const float* ap = hp + (size_t)(m0 + a15) * H_ + g;   // A: h[m0+a15][kc+g]
    const float* bp = W1T + (size_t)g * H_ + oc + a15;    // B: W1T[kc+g][oc+ot*16+a15]

    d4 acc[4];
    #pragma unroll
    for (int ot = 0; ot < 4; ++ot) acc[ot] = (d4){0.0, 0.0, 0.0, 0.0};

    float ac0, ac1, bc[8];
    ac0 = ap[0];
    ac1 = ap[4];
    #pragma unroll
    for (int ot = 0; ot < 4; ++ot) {
        bc[ot]     = bp[ot * 16];
        bc[4 + ot] = bp[4 * H_ + ot * 16];
    }

    for (int kc = 0; kc < H_; kc += 8) {
        const int kn = (kc + 8 < H_) ? (kc + 8) : 0;      // guarded prefetch
        const float an0 = ap[kn];
        const float an1 = ap[kn + 4];
        float bn[8];
        #pragma unroll
        for (int ot = 0; ot < 4; ++ot) {
            bn[ot]     = bp[(size_t)kn * H_ + ot * 16];
            bn[4 + ot] = bp[(size_t)(kn + 4) * H_ + ot * 16];
        }
        const double av0 = (double)ac0;
        #pragma unroll
        for (int ot = 0; ot < 4; ++ot)
            acc[ot] = __builtin_amdgcn_mfma_f64_16x16x4f64(
                av0, (double)bc[ot], acc[ot], 0, 0, 0);
        const double av1 = (double)ac1;
        #pragma unroll
        for (int ot = 0; ot < 4; ++ot)
            acc[ot] = __builtin_amdgcn_mfma_f64_16x16x4f64(
                av1, (double)bc[4 + ot], acc[ot], 0, 0, 0);
        ac0 = an0; ac1 = an1;
        #pragma unroll
        for (int q = 0; q < 8; ++q) bc[q] = bn[q];
    }

    if (var == 1 || var == 3) {
        // col = a15 (fixed per lane); row = 4g+v (var 1) or g+4v (var 3).
        double psum[4] = {0.0, 0.0, 0.0, 0.0};
        #pragma unroll
        for (int ot = 0; ot < 4; ++ot) {
            const int o = oc + ot * 16 + a15;
            const double bb = (double)b1[o];
            const double ww = (double)w2[o];
            #pragma unroll
            for (int v = 0; v < 4; ++v) {
                const double u = acc[ot][v] + bb;
                psum[v] += ww * (u / (1.0 + exp(-u)));
            }
        }
        #pragma unroll
        for (int v = 0; v < 4; ++v) {
            double x = psum[v];
            x += __shfl_xor(x, 1, 64);
            x += __shfl_xor(x, 2, 64);
            x += __shfl_xor(x, 4, 64);
            x += __shfl_xor(x, 8, 64);
            psum[v] = x;
        }
        if (a15 == 0) {
            #pragma unroll
            for (int v = 0; v < 4; ++v) {
                const int row = (var == 1) ? (g * 4 + v) : (g + 4 * v);
                spart[wave][row] = psum[v];
            }
        }
    } else {
        // row = a15 (fixed per lane); col = 4g+v (var 2) or g+4v (var 4).
        double ps = 0.0;
        #pragma unroll
        for (int ot = 0; ot < 4; ++ot) {
            #pragma unroll
            for (int v = 0; v < 4; ++v) {
                const int cv = (var == 2) ? (4 * g + v) : (g + 4 * v);
                const int o = oc + ot * 16 + cv;
                const double u = acc[ot][v] + (double)b1[o];
                ps += (double)w2[o] * (u / (1.0 + exp(-u)));
            }
        }
        ps += __shfl_xor(ps, 16, 64);
        ps += __shfl_xor(ps, 32, 64);
        if (g == 0) spart[wave][a15] = ps;
    }
    __syncthreads();
    if (t < 16)
        s_out[m0 + t] = spart[0][t] + spart[1][t] + spart[2][t] + spart[3][t];
}

// VALU fallback (round-11 verified body): runs only if NO variant matched.
__global__ __launch_bounds__(256)
__attribute__((amdgpu_waves_per_eu(2, 4)))
void s_valu_kernel(const float* __restrict__ hp, const float* __restrict__ W1T,
                   const float* __restrict__ b1, const float* __restrict__ w2,
                   double* __restrict__ s_out, const double* __restrict__ pw) {
    if (layout_var(pw) != 0) return;
    const int t = threadIdx.x;
    const int lane = t & 63;
    const int wave = __builtin_amdgcn_readfirstlane(t >> 6);
    const int m0 = blockIdx.x * 16 + wave * 4;
    const int o0 = lane * 4;
    const float* hr = hp + (size_t)m0 * H_;
    const float* wp = W1T + o0;

    double acc[4][4];
    #pragma unroll
    for (int j = 0; j < 4; ++j)
        #pragma unroll
        for (int r = 0; r < 4; ++r) acc[j][r] = 0.0;

    float4 wA[8], wB[8];
    float hA[32], hB[32];

    #define LOADW(dst, kcv)                                                   \
        do {                                                                  \
            _Pragma("unroll")                                                 \
            for (int kk = 0; kk < 8; ++kk)                                    \
                dst[kk] = *reinterpret_cast<const float4*>(                   \
                    wp + (size_t)((kcv) + kk) * H_);                          \
        } while (0)

    #define LOADH(dst, kcv)                                                   \
        do {                                                                  \
            _Pragma("unroll")                                                 \
            for (int r = 0; r < 4; ++r)                                       \
                _Pragma("unroll")                                             \
                for (int kk = 0; kk < 8; ++kk)                                \
                    dst[r * 8 + kk] = hr[r * H_ + (kcv) + kk];                \
        } while (0)

    #define COMPUTE(wv, hbuf)                                                 \
        do {                                                                  \
            _Pragma("unroll")                                                 \
            for (int kk = 0; kk < 8; ++kk) {                                  \
                const double h0 = (double)hbuf[0 * 8 + kk];                   \
                const double h1 = (double)hbuf[1 * 8 + kk];                   \
                const double h2 = (double)hbuf[2 * 8 + kk];                   \
                const double h3 = (double)hbuf[3 * 8 + kk];                   \
                const double a0 = (double)wv[kk].x;                           \
                const double a1 = (double)wv[kk].y;                           \
                const double a2 = (double)wv[kk].z;                           \
                const double a3 = (double)wv[kk].w;                           \
                acc[0][0] = fma(a0, h0, acc[0][0]);                           \
                acc[0][1] = fma(a0, h1, acc[0][1]);                           \
                acc[0][2] = fma(a0, h2, acc[0][2]);                           \
                acc[0][3] = fma(a0, h3, acc[0][3]);                           \
                acc[1][0] = fma(a1, h0, acc[1][0]);                           \
                acc[1][1] = fma(a1, h1, acc[1][1]);                           \
                acc[1][2] = fma(a1, h2, acc[1][2]);                           \
                acc[1][3] = fma(a1, h3, acc[1][3]);                           \
                acc[2][0] = fma(a2, h0, acc[2][0]);                           \
                acc[2][1] = fma(a2, h1, acc[2][1]);                           \
                acc[2][2] = fma(a2, h2, acc[2][2]);                           \
                acc[2][3] = fma(a2, h3, acc[2][3]);                           \
                acc[3][0] = fma(a3, h0, acc[3][0]);                           \
                acc[3][1] = fma(a3, h1, acc[3][1]);                           \
                acc[3][2] = fma(a3, h2, acc[3][2]);                           \
                acc[3][3] = fma(a3, h3, acc[3][3]);                           \
            }                                                                 \
        } while (0)

    LOADW(wA, 0);
    LOADH(hA, 0);
    for (int kc = 0; kc < H_; kc += 16) {
        LOADW(wB, kc + 8);
        LOADH(hB, kc + 8);
        COMPUTE(wA, hA);
        if (kc + 16 < H_) {
            LOADW(wA, kc + 16);
            LOADH(hA, kc + 16);
        }
        COMPUTE(wB, hB);
    }
    #undef LOADW
    #undef LOADH
    #undef COMPUTE

    const float4 b1v = *reinterpret_cast<const float4*>(b1 + o0);
    const float4 w2v = *reinterpret_cast<const float4*>(w2 + o0);
    double psum[4] = {0.0, 0.0, 0.0, 0.0};
    #define EPI(j, bc, wc)                                                    \
        do {                                                                  \
            const double bb = (double)bc, ww = (double)wc;                    \
            _Pragma("unroll")                                                 \
            for (int r = 0; r < 4; ++r) {                                     \
                const double u = acc[j][r] + bb;                              \
                psum[r] += ww * (u / (1.0 + exp(-u)));                        \
            }                                                                 \
        } while (0)
    EPI(0, b1v.x, w2v.x);
    EPI(1, b1v.y, w2v.y);
    EPI(2, b1v.z, w2v.z);
    EPI(3, b1v.w, w2v.w);
    #undef EPI

    #pragma unroll
    for (int r = 0; r < 4; ++r) {
        double v = psum[r];
        v += __shfl_xor(v, 1, 64);
        v += __shfl_xor(v, 2, 64);
        v += __shfl_xor(v, 4, 64);
        v += __shfl_xor(v, 8, 64);
        v += __shfl_xor(v, 16, 64);
        v += __shfl_xor(v, 32, 64);
        if (lane == 0) s_out[m0 + r] = v;
    }
}

// Kernel B: out[b,i,j] = (int32)trunc( (s[b,i] - s[b,j]) + b2 )
__global__ __launch_bounds__(256)
void pair_kernel(const double* __restrict__ s, const float* __restrict__ b2p,
                 int* __restrict__ out) {
    const double b2 = (double)b2p[0];
    const unsigned total4 = (unsigned)(B_) * (unsigned)(N_) * (unsigned)(N_) / 4u;
    const unsigned stride = gridDim.x * blockDim.x;
    for (unsigned idx = blockIdx.x * blockDim.x + threadIdx.x; idx < total4;
         idx += stride) {
        const unsigned base = idx * 4u;                 // element index, %4==0
        const unsigned bi  = base >> 22;                // / (N*N), N*N = 2^22
        const unsigned rem = base & ((1u << 22) - 1u);
        const unsigned i   = rem >> 11;                 // / N
        const unsigned j   = rem & (N_ - 1u);
        const double si = s[bi * N_ + i];
        const double* sp = s + bi * N_ + j;             // 32B aligned (j%4==0)
        const double sj0 = sp[0], sj1 = sp[1], sj2 = sp[2], sj3 = sp[3];
        int4 o;
        o.x = (int)trunc((si - sj0) + b2);
        o.y = (int)trunc((si - sj1) + b2);
        o.z = (int)trunc((si - sj2) + b2);
        o.w = (int)trunc((si - sj3) + b2);
        *reinterpret_cast<int4*>(out + base) = o;
    }
}

extern "C" void kernel_launch(void* const* d_in, const int* in_sizes, int n_in,
                              void* d_out, int out_size, void* d_ws, size_t ws_size,
                              hipStream_t stream) {
    const float* hp = (const float*)d_in[0];
    // d_in[1] = node_mask (unused), d_in[2] = n_nodes (unused)
    const float* W1 = (const float*)d_in[3];
    const float* b1 = (const float*)d_in[4];
    const float* w2 = (const float*)d_in[5];
    const float* b2 = (const float*)d_in[6];

    float*  W1T = (float*)d_ws;                                       // 256 KB
    double* s   = (double*)((char*)d_ws + H_ * H_ * sizeof(float));   // 128 KB
    double* pw  = (double*)((char*)d_ws + 384 * 1024);                // 64 B
    int* out = (int*)d_out;

    probe_kernel<<<1, 64, 0, stream>>>(pw);
    transpose_w1<<<H_, H_, 0, stream>>>(W1, W1T);
    s_mfma_uni<<<(B_ * N_) / 16, 256, 0, stream>>>(hp, W1T, b1, w2, s, pw);
    s_valu_kernel<<<(B_ * N_) / 16, 256, 0, stream>>>(hp, W1T, b1, w2, s, pw);
    pair_kernel<<<2048, 256, 0, stream>>>(s, b2, out);
}

// Round 17
// 74.623 us; speedup vs baseline: 1.3289x; 1.0924x over previous
//
#include <hip/hip_runtime.h>
#include <math.h>

#define B_ 8
#define N_ 2048
#define H_ 256

typedef double d4 __attribute__((ext_vector_type(4)));

// One-shot: W1T[k][o] = W1[o][k] (f32, 256 KB in d_ws) -> unit-stride reads.
__global__ __launch_bounds__(256)
void transpose_w1(const float* __restrict__ W1, float* __restrict__ W1T) {
    W1T[(size_t)blockIdx.x * H_ + threadIdx.x] =
        W1[(size_t)threadIdx.x * H_ + blockIdx.x];
}

// In-kernel probe of the v_mfma_f64_16x16x4_f64 lane mapping (~200 cy).
// Sentinels as rounds 14-16 (round 15/16 proved one of vars 1-4 matches):
//  r1=mfma(l+1,1): D[i][j]=4i+100 -> lane0.reg0 = 100 iff A std.
//  r2=mfma(1,l+1): D[i][j]=4j+100 -> lane0.reg0 = 100 iff B std;
//     lane16.reg2 = 124 (col=4g+v) / 136 (col=g+4v) / 100 (col=a15).
//  r3=mfma(l&15,1): D[i][j]=4i -> lane1.reg0 = 0 (row from g,v) or 4 (row=a15);
//     lane16.reg2 = 24 (row=4g+v) / 36 (row=g+4v).
__device__ __forceinline__ int self_probe_var() {
    const int l = threadIdx.x & 63;
    d4 z = {0.0, 0.0, 0.0, 0.0};
    d4 r1 = __builtin_amdgcn_mfma_f64_16x16x4f64((double)(l + 1), 1.0, z, 0, 0, 0);
    d4 r2 = __builtin_amdgcn_mfma_f64_16x16x4f64(1.0, (double)(l + 1), z, 0, 0, 0);
    d4 r3 = __builtin_amdgcn_mfma_f64_16x16x4f64((double)(l & 15), 1.0, z, 0, 0, 0);
    const double pw0 = __shfl(r1[0], 0, 64);
    const double pw1 = __shfl(r2[0], 0, 64);
    const double pw2 = __shfl(r3[0], 1, 64);
    const double pw3 = __shfl(r3[2], 16, 64);
    const double pw4 = __shfl(r2[2], 16, 64);
    if (pw0 != 100.0 || pw1 != 100.0) return 0;
    if (pw2 == 0.0 && pw3 == 24.0)  return 1;   // row=4g+v, col=a15
    if (pw2 == 0.0 && pw3 == 36.0)  return 3;   // row=g+4v, col=a15
    if (pw2 == 4.0 && pw4 == 124.0) return 2;   // row=a15,  col=4g+v
    if (pw2 == 4.0 && pw4 == 136.0) return 4;   // row=a15,  col=g+4v
    return 0;
}

// MFMA s-kernel. 32 rows/block (grid 512), 4 waves; wave = 2 m-tiles x 4
// o-tiles (64-o strip). Inner loop: 8 k = 16 mfma (8 indep acc chains)
// against 12 loads (4 A + 8 B, B shared across the 2 m-tiles), prefetched
// one iteration ahead. GEMM body is mapping-independent; epilogue branches
// on the wave-uniform variant.
__global__ __launch_bounds__(256)
__attribute__((amdgpu_waves_per_eu(2, 4)))
void s_mfma_uni(const float* __restrict__ hp, const float* __restrict__ W1T,
                const float* __restrict__ b1, const float* __restrict__ w2,
                double* __restrict__ s_out) {
    const int var = self_probe_var();
    if (var == 0) return;                       // VALU fallback does the work
    __shared__ double spart[4][32];
    const int t = threadIdx.x;
    const int lane = t & 63;
    const int wave = __builtin_amdgcn_readfirstlane(t >> 6);
    const int a15 = lane & 15, g = lane >> 4;
    const int m0 = blockIdx.x * 32;
    const int oc = wave * 64;
    const float* ap0 = hp + (size_t)(m0 + a15) * H_ + g;        // m-tile 0
    const float* ap1 = hp + (size_t)(m0 + 16 + a15) * H_ + g;   // m-tile 1
    const float* bp  = W1T + (size_t)g * H_ + oc + a15;

    d4 acc[2][4];
    #pragma unroll
    for (int mt = 0; mt < 2; ++mt)
        #pragma unroll
        for (int ot = 0; ot < 4; ++ot) acc[mt][ot] = (d4){0.0, 0.0, 0.0, 0.0};

    float ac[4], an[4];        // A: [mt*2 + half]
    float bcv[8], bnv[8];      // B: [half*4 + ot]
    ac[0] = ap0[0]; ac[1] = ap0[4]; ac[2] = ap1[0]; ac[3] = ap1[4];
    #pragma unroll
    for (int ot = 0; ot < 4; ++ot) {
        bcv[ot]     = bp[ot * 16];
        bcv[4 + ot] = bp[4 * H_ + ot * 16];
    }

    for (int kc = 0; kc < H_; kc += 8) {
        const int kn = (kc + 8 < H_) ? (kc + 8) : 0;      // guarded prefetch
        an[0] = ap0[kn]; an[1] = ap0[kn + 4];
        an[2] = ap1[kn]; an[3] = ap1[kn + 4];
        #pragma unroll
        for (int ot = 0; ot < 4; ++ot) {
            bnv[ot]     = bp[(size_t)kn * H_ + ot * 16];
            bnv[4 + ot] = bp[(size_t)(kn + 4) * H_ + ot * 16];
        }
        {   // k half 0 (k = kc..kc+3)
            const double a0 = (double)ac[0], a1 = (double)ac[2];
            #pragma unroll
            for (int ot = 0; ot < 4; ++ot) {
                const double bv = (double)bcv[ot];
                acc[0][ot] = __builtin_amdgcn_mfma_f64_16x16x4f64(a0, bv, acc[0][ot], 0, 0, 0);
                acc[1][ot] = __builtin_amdgcn_mfma_f64_16x16x4f64(a1, bv, acc[1][ot], 0, 0, 0);
            }
        }
        {   // k half 1 (k = kc+4..kc+7)
            const double a0 = (double)ac[1], a1 = (double)ac[3];
            #pragma unroll
            for (int ot = 0; ot < 4; ++ot) {
                const double bv = (double)bcv[4 + ot];
                acc[0][ot] = __builtin_amdgcn_mfma_f64_16x16x4f64(a0, bv, acc[0][ot], 0, 0, 0);
                acc[1][ot] = __builtin_amdgcn_mfma_f64_16x16x4f64(a1, bv, acc[1][ot], 0, 0, 0);
            }
        }
        #pragma unroll
        for (int q = 0; q < 4; ++q) ac[q] = an[q];
        #pragma unroll
        for (int q = 0; q < 8; ++q) bcv[q] = bnv[q];
    }

    if (var == 1 || var == 3) {
        // col = a15 (fixed per lane); row = 4g+v (var 1) or g+4v (var 3).
        double psum[2][4];
        #pragma unroll
        for (int mt = 0; mt < 2; ++mt)
            #pragma unroll
            for (int v = 0; v < 4; ++v) psum[mt][v] = 0.0;
        #pragma unroll
        for (int ot = 0; ot < 4; ++ot) {
            const int o = oc + ot * 16 + a15;
            const double bb = (double)b1[o];
            const double ww = (double)w2[o];
            #pragma unroll
            for (int mt = 0; mt < 2; ++mt)
                #pragma unroll
                for (int v = 0; v < 4; ++v) {
                    const double u = acc[mt][ot][v] + bb;
                    psum[mt][v] += ww * (u / (1.0 + exp(-u)));
                }
        }
        #pragma unroll
        for (int mt = 0; mt < 2; ++mt)
            #pragma unroll
            for (int v = 0; v < 4; ++v) {
                double x = psum[mt][v];
                x += __shfl_xor(x, 1, 64);
                x += __shfl_xor(x, 2, 64);
                x += __shfl_xor(x, 4, 64);
                x += __shfl_xor(x, 8, 64);
                psum[mt][v] = x;
            }
        if (a15 == 0) {
            #pragma unroll
            for (int mt = 0; mt < 2; ++mt)
                #pragma unroll
                for (int v = 0; v < 4; ++v) {
                    const int row = (var == 1) ? (4 * g + v) : (g + 4 * v);
                    spart[wave][mt * 16 + row] = psum[mt][v];
                }
        }
    } else {
        // row = a15 (fixed per lane); col = 4g+v (var 2) or g+4v (var 4).
        double ps[2] = {0.0, 0.0};
        #pragma unroll
        for (int ot = 0; ot < 4; ++ot)
            #pragma unroll
            for (int v = 0; v < 4; ++v) {
                const int cv = (var == 2) ? (4 * g + v) : (g + 4 * v);
                const int o = oc + ot * 16 + cv;
                const double bb = (double)b1[o];
                const double ww = (double)w2[o];
                #pragma unroll
                for (int mt = 0; mt < 2; ++mt) {
                    const double u = acc[mt][ot][v] + bb;
                    ps[mt] += ww * (u / (1.0 + exp(-u)));
                }
            }
        #pragma unroll
        for (int mt = 0; mt < 2; ++mt) {
            ps[mt] += __shfl_xor(ps[mt], 16, 64);
            ps[mt] += __shfl_xor(ps[mt], 32, 64);
        }
        if (g == 0) {
            spart[wave][a15]      = ps[0];
            spart[wave][16 + a15] = ps[1];
        }
    }
    __syncthreads();
    if (t < 32)
        s_out[m0 + t] = spart[0][t] + spart[1][t] + spart[2][t] + spart[3][t];
}

// VALU fallback (round-11 verified body): runs only if self-probe found no
// known variant.
__global__ __launch_bounds__(256)
__attribute__((amdgpu_waves_per_eu(2, 4)))
void s_valu_kernel(const float* __restrict__ hp, const float* __restrict__ W1T,
                   const float* __restrict__ b1, const float* __restrict__ w2,
                   double* __restrict__ s_out) {
    if (self_probe_var() != 0) return;
    const int t = threadIdx.x;
    const int lane = t & 63;
    const int wave = __builtin_amdgcn_readfirstlane(t >> 6);
    const int m0 = blockIdx.x * 16 + wave * 4;
    const int o0 = lane * 4;
    const float* hr = hp + (size_t)m0 * H_;
    const float* wp = W1T + o0;

    double acc[4][4];
    #pragma unroll
    for (int j = 0; j < 4; ++j)
        #pragma unroll
        for (int r = 0; r < 4; ++r) acc[j][r] = 0.0;

    float4 wA[8], wB[8];
    float hA[32], hB[32];

    #define LOADW(dst, kcv)                                                   \
        do {                                                                  \
            _Pragma("unroll")                                                 \
            for (int kk = 0; kk < 8; ++kk)                                    \
                dst[kk] = *reinterpret_cast<const float4*>(                   \
                    wp + (size_t)((kcv) + kk) * H_);                          \
        } while (0)

    #define LOADH(dst, kcv)                                                   \
        do {                                                                  \
            _Pragma("unroll")                                                 \
            for (int r = 0; r < 4; ++r)                                       \
                _Pragma("unroll")                                             \
                for (int kk = 0; kk < 8; ++kk)                                \
                    dst[r * 8 + kk] = hr[r * H_ + (kcv) + kk];                \
        } while (0)

    #define COMPUTE(wv, hbuf)                                                 \
        do {                                                                  \
            _Pragma("unroll")                                                 \
            for (int kk = 0; kk < 8; ++kk) {                                  \
                const double h0 = (double)hbuf[0 * 8 + kk];                   \
                const double h1 = (double)hbuf[1 * 8 + kk];                   \
                const double h2 = (double)hbuf[2 * 8 + kk];                   \
                const double h3 = (double)hbuf[3 * 8 + kk];                   \
                const double a0 = (double)wv[kk].x;                           \
                const double a1 = (double)wv[kk].y;                           \
                const double a2 = (double)wv[kk].z;                           \
                const double a3 = (double)wv[kk].w;                           \
                acc[0][0] = fma(a0, h0, acc[0][0]);                           \
                acc[0][1] = fma(a0, h1, acc[0][1]);                           \
                acc[0][2] = fma(a0, h2, acc[0][2]);                           \
                acc[0][3] = fma(a0, h3, acc[0][3]);                           \
                acc[1][0] = fma(a1, h0, acc[1][0]);                           \
                acc[1][1] = fma(a1, h1, acc[1][1]);                           \
                acc[1][2] = fma(a1, h2, acc[1][2]);                           \
                acc[1][3] = fma(a1, h3, acc[1][3]);                           \
                acc[2][0] = fma(a2, h0, acc[2][0]);                           \
                acc[2][1] = fma(a2, h1, acc[2][1]);                           \
                acc[2][2] = fma(a2, h2, acc[2][2]);                           \
                acc[2][3] = fma(a2, h3, acc[2][3]);                           \
                acc[3][0] = fma(a3, h0, acc[3][0]);                           \
                acc[3][1] = fma(a3, h1, acc[3][1]);                           \
                acc[3][2] = fma(a3, h2, acc[3][2]);                           \
                acc[3][3] = fma(a3, h3, acc[3][3]);                           \
            }                                                                 \
        } while (0)

    LOADW(wA, 0);
    LOADH(hA, 0);
    for (int kc = 0; kc < H_; kc += 16) {
        LOADW(wB, kc + 8);
        LOADH(hB, kc + 8);
        COMPUTE(wA, hA);
        if (kc + 16 < H_) {
            LOADW(wA, kc + 16);
            LOADH(hA, kc + 16);
        }
        COMPUTE(wB, hB);
    }
    #undef LOADW
    #undef LOADH
    #undef COMPUTE

    const float4 b1v = *reinterpret_cast<const float4*>(b1 + o0);
    const float4 w2v = *reinterpret_cast<const float4*>(w2 + o0);
    double psum[4] = {0.0, 0.0, 0.0, 0.0};
    #define EPI(j, bc, wc)                                                    \
        do {                                                                  \
            const double bb = (double)bc, ww = (double)wc;                    \
            _Pragma("unroll")                                                 \
            for (int r = 0; r < 4; ++r) {                                     \
                const double u = acc[j][r] + bb;                              \
                psum[r] += ww * (u / (1.0 + exp(-u)));                        \
            }                                                                 \
        } while (0)
    EPI(0, b1v.x, w2v.x);
    EPI(1, b1v.y, w2v.y);
    EPI(2, b1v.z, w2v.z);
    EPI(3, b1v.w, w2v.w);
    #undef EPI

    #pragma unroll
    for (int r = 0; r < 4; ++r) {
        double v = psum[r];
        v += __shfl_xor(v, 1, 64);
        v += __shfl_xor(v, 2, 64);
        v += __shfl_xor(v, 4, 64);
        v += __shfl_xor(v, 8, 64);
        v += __shfl_xor(v, 16, 64);
        v += __shfl_xor(v, 32, 64);
        if (lane == 0) s_out[m0 + r] = v;
    }
}

// Kernel B: out[b,i,j] = (int32)trunc( (s[b,i] - s[b,j]) + b2 )
__global__ __launch_bounds__(256)
void pair_kernel(const double* __restrict__ s, const float* __restrict__ b2p,
                 int* __restrict__ out) {
    const double b2 = (double)b2p[0];
    const unsigned total4 = (unsigned)(B_) * (unsigned)(N_) * (unsigned)(N_) / 4u;
    const unsigned stride = gridDim.x * blockDim.x;
    for (unsigned idx = blockIdx.x * blockDim.x + threadIdx.x; idx < total4;
         idx += stride) {
        const unsigned base = idx * 4u;                 // element index, %4==0
        const unsigned bi  = base >> 22;                // / (N*N), N*N = 2^22
        const unsigned rem = base & ((1u << 22) - 1u);
        const unsigned i   = rem >> 11;                 // / N
        const unsigned j   = rem & (N_ - 1u);
        const double si = s[bi * N_ + i];
        const double* sp = s + bi * N_ + j;             // 32B aligned (j%4==0)
        const double sj0 = sp[0], sj1 = sp[1], sj2 = sp[2], sj3 = sp[3];
        int4 o;
        o.x = (int)trunc((si - sj0) + b2);
        o.y = (int)trunc((si - sj1) + b2);
        o.z = (int)trunc((si - sj2) + b2);
        o.w = (int)trunc((si - sj3) + b2);
        *reinterpret_cast<int4*>(out + base) = o;
    }
}

extern "C" void kernel_launch(void* const* d_in, const int* in_sizes, int n_in,
                              void* d_out, int out_size, void* d_ws, size_t ws_size,
                              hipStream_t stream) {
    const float* hp = (const float*)d_in[0];
    // d_in[1] = node_mask (unused), d_in[2] = n_nodes (unused)
    const float* W1 = (const float*)d_in[3];
    const float* b1 = (const float*)d_in[4];
    const float* w2 = (const float*)d_in[5];
    const float* b2 = (const float*)d_in[6];

    float*  W1T = (float*)d_ws;                                       // 256 KB
    double* s   = (double*)((char*)d_ws + H_ * H_ * sizeof(float));   // 128 KB
    int* out = (int*)d_out;

    transpose_w1<<<H_, H_, 0, stream>>>(W1, W1T);
    s_mfma_uni<<<(B_ * N_) / 32, 256, 0, stream>>>(hp, W1T, b1, w2, s);
    s_valu_kernel<<<(B_ * N_) / 16, 256, 0, stream>>>(hp, W1T, b1, w2, s);
    pair_kernel<<<2048, 256, 0, stream>>>(s, b2, out);
}